// Round 3
// baseline (1721.233 us; speedup 1.0000x reference)
//
#include <hip/hip_runtime.h>
#include <hip/hip_bf16.h>
#include <math.h>

#define HIDDEN 4096
#define HALF   2048
#define NE     64
#define TOPK   8

typedef __attribute__((ext_vector_type(8))) short          short8;
typedef __attribute__((ext_vector_type(4))) float          floatx4;
typedef __attribute__((ext_vector_type(4))) unsigned short ushort4v;

// ---------- bf16 split helpers ------------------------------------------------
__device__ inline unsigned short bf16_rne(float v) {
    union { float f; unsigned u; } x; x.f = v;
    unsigned r = x.u + 0x7fffu + ((x.u >> 16) & 1u);
    return (unsigned short)(r >> 16);
}
__device__ inline float bf16_to_f(unsigned short b) {
    union { unsigned u; float f; } x; x.u = (unsigned)b << 16;
    return x.f;
}

// ---------- h storage precision helpers ---------------------------------------
__device__ inline void hstore(float* p, float v) { *p = v; }
__device__ inline void hstore(__hip_bfloat16* p, float v) { *p = __float2bfloat16(v); }
__device__ inline float hload(const float* p) { return *p; }
__device__ inline float hload(const __hip_bfloat16* p) { return __bfloat162float(*p); }

// ---------- async global->LDS, 16B per lane -----------------------------------
__device__ inline void gl2lds16(const void* g, void* l) {
    __builtin_amdgcn_global_load_lds(
        (const __attribute__((address_space(1))) void*)g,
        (__attribute__((address_space(3))) void*)l, 16, 0, 0);
}

// ---------------------------------------------------------------------------
// P1: split x[T*4096] fp32 -> xh, xl bf16 (4 elems/thread)
// ---------------------------------------------------------------------------
__global__ __launch_bounds__(256) void split_x_k(const float* __restrict__ x,
                                                 unsigned short* __restrict__ hi,
                                                 unsigned short* __restrict__ lo) {
    const size_t i = ((size_t)blockIdx.x * 256 + threadIdx.x) * 4;
    float4 v = *(const float4*)(x + i);
    const float vs[4] = {v.x, v.y, v.z, v.w};
    ushort4v h4, l4;
#pragma unroll
    for (int j = 0; j < 4; ++j) {
        unsigned short hb = bf16_rne(vs[j]);
        h4[j] = hb;
        l4[j] = bf16_rne(vs[j] - bf16_to_f(hb));
    }
    *(ushort4v*)(hi + i) = h4;
    *(ushort4v*)(lo + i) = l4;
}

// ---------------------------------------------------------------------------
// P2: W1[4096][2048] fp32 -> transposed wh, wl [2048][4096] bf16.
// 64x64 LDS tile transpose, 2048 blocks x 256 thr.
// ---------------------------------------------------------------------------
__global__ __launch_bounds__(256) void split_wt_k(const float* __restrict__ W1,
                                                  unsigned short* __restrict__ wh,
                                                  unsigned short* __restrict__ wl) {
    __shared__ float tile[64][65];
    const int tid = threadIdx.x;
    const int bk = blockIdx.x * 64, bn = blockIdx.y * 64;
    const int c4 = (tid & 15) * 4, r = tid >> 4;   // r in 0..15
#pragma unroll
    for (int rr = 0; rr < 4; ++rr) {
        const int row = r + rr * 16;
        *(float4*)&tile[row][c4] = *(const float4*)&W1[(size_t)(bk + row) * HALF + bn + c4];
    }
    __syncthreads();
#pragma unroll
    for (int rr = 0; rr < 4; ++rr) {
        const int n = r + rr * 16;
        ushort4v h4, l4;
#pragma unroll
        for (int j = 0; j < 4; ++j) {
            float v = tile[c4 + j][n];
            unsigned short hb = bf16_rne(v);
            h4[j] = hb;
            l4[j] = bf16_rne(v - bf16_to_f(hb));
        }
        *(ushort4v*)&wh[(size_t)(bn + n) * HIDDEN + bk + c4] = h4;
        *(ushort4v*)&wl[(size_t)(bn + n) * HIDDEN + bk + c4] = l4;
    }
}

// ---------------------------------------------------------------------------
// K1 (pre-split): h = gelu_exact(x @ W1 + b1), 3-pass split-bf16 MFMA.
// xh/xl [T][4096] bf16 row-major; wh/wl [2048][4096] bf16 (n-major = W1^T).
// 128x128 tile, BK=32, 4 waves, wave tile 64x64 (4x4 of 16x16x32).
// Staging via global_load_lds width=16: wave w stages array w (Ah/Al/Bh/Bl),
// 8 shots x 16 rows; LDS rows are 32 shorts (64B) unpadded -> frag b128 reads
// are a permutation of a contiguous 1KB window per 16-row tile: conflict-free.
// ---------------------------------------------------------------------------
__global__ __launch_bounds__(256, 2) void gemm1_gelu_pre(const unsigned short* __restrict__ xh,
                                                         const unsigned short* __restrict__ xl,
                                                         const unsigned short* __restrict__ wh,
                                                         const unsigned short* __restrict__ wl,
                                                         const float* __restrict__ bias1,
                                                         float* __restrict__ h) {
    __shared__ unsigned short Ah[128][32];
    __shared__ unsigned short Al[128][32];
    __shared__ unsigned short Bh[128][32];
    __shared__ unsigned short Bl[128][32];

    const int tid  = threadIdx.x;
    const int m0   = blockIdx.x * 128;
    const int n0   = blockIdx.y * 128;
    const int wave = tid >> 6, lane = tid & 63;
    const int wm   = (wave & 1) * 64;
    const int wn   = (wave >> 1) * 64;
    const int l15  = lane & 15;
    const int q    = lane >> 4;

    // staging: wave -> one array; lane covers row lane/4, elems (lane&3)*8
    const size_t lrow = (size_t)(lane >> 2);
    const int    lcol = (lane & 3) * 8;
    const unsigned short* gp;
    unsigned short* lp;
    if (wave == 0)      { gp = xh + (m0 + lrow) * HIDDEN + lcol; lp = &Ah[0][0]; }
    else if (wave == 1) { gp = xl + (m0 + lrow) * HIDDEN + lcol; lp = &Al[0][0]; }
    else if (wave == 2) { gp = wh + (n0 + lrow) * HIDDEN + lcol; lp = &Bh[0][0]; }
    else                { gp = wl + (n0 + lrow) * HIDDEN + lcol; lp = &Bl[0][0]; }

    floatx4 acc[4][4];
#pragma unroll
    for (int i = 0; i < 4; ++i)
#pragma unroll
        for (int j = 0; j < 4; ++j) acc[i][j] = (floatx4)0.f;

    for (int k0 = 0; k0 < HIDDEN; k0 += 32) {
        __syncthreads();   // previous iteration's frag reads complete
#pragma unroll
        for (int s = 0; s < 8; ++s)
            gl2lds16(gp + (size_t)s * 16 * HIDDEN, lp + s * 512);
        gp += 32;
        __syncthreads();   // drain global_load_lds

        short8 a_hi[4], a_lo[4], b_hi[4], b_lo[4];
#pragma unroll
        for (int t = 0; t < 4; ++t) {
            a_hi[t] = *(const short8*)&Ah[wm + t * 16 + l15][q * 8];
            a_lo[t] = *(const short8*)&Al[wm + t * 16 + l15][q * 8];
            b_hi[t] = *(const short8*)&Bh[wn + t * 16 + l15][q * 8];
            b_lo[t] = *(const short8*)&Bl[wn + t * 16 + l15][q * 8];
        }
#pragma unroll
        for (int i = 0; i < 4; ++i)
#pragma unroll
            for (int j = 0; j < 4; ++j) {
                acc[i][j] = __builtin_amdgcn_mfma_f32_16x16x32_bf16(a_hi[i], b_hi[j], acc[i][j], 0, 0, 0);
                acc[i][j] = __builtin_amdgcn_mfma_f32_16x16x32_bf16(a_lo[i], b_hi[j], acc[i][j], 0, 0, 0);
                acc[i][j] = __builtin_amdgcn_mfma_f32_16x16x32_bf16(a_hi[i], b_lo[j], acc[i][j], 0, 0, 0);
            }
    }

    // epilogue: +bias, exact GELU. C/D: col=lane&15, row=(lane>>4)*4+reg.
#pragma unroll
    for (int j = 0; j < 4; ++j) {
        const int n = n0 + wn + j * 16 + l15;
        const float bb = bias1[n];
#pragma unroll
        for (int i = 0; i < 4; ++i) {
            const int mbase = m0 + wm + i * 16 + q * 4;
#pragma unroll
            for (int r = 0; r < 4; ++r) {
                float v = acc[i][j][r] + bb;
                float g = 0.5f * v * (1.0f + erff(v * 0.70710678118654752f));
                h[(size_t)(mbase + r) * HALF + n] = g;
            }
        }
    }
}

// ---------------------------------------------------------------------------
// K1 fallback (round-2): in-kernel conversion. Used when ws is too small.
// ---------------------------------------------------------------------------
template <typename HT>
__global__ __launch_bounds__(256, 2) void gemm1_gelu_mfma(const float* __restrict__ x,
                                                          const float* __restrict__ W1,
                                                          const float* __restrict__ bias1,
                                                          HT* __restrict__ h) {
    __shared__ unsigned short Ah[128][40];
    __shared__ unsigned short Al[128][40];
    __shared__ unsigned short Bh[128][40];
    __shared__ unsigned short Bl[128][40];

    const int tid  = threadIdx.x;
    const int m0   = blockIdx.x * 128;
    const int n0   = blockIdx.y * 128;
    const int wave = tid >> 6, lane = tid & 63;
    const int wm   = (wave & 1) * 64;
    const int wn   = (wave >> 1) * 64;
    const int l15  = lane & 15;
    const int q    = lane >> 4;
    const int sm = tid & 127;
    const int kh = (tid >> 7) * 16;

    floatx4 acc[4][4];
#pragma unroll
    for (int i = 0; i < 4; ++i)
#pragma unroll
        for (int j = 0; j < 4; ++j) acc[i][j] = (floatx4)0.f;

    const float* xp = x  + (size_t)(m0 + sm) * HIDDEN + kh;
    const float* wp = W1 + (size_t)kh * HALF + n0 + sm;

    for (int k0 = 0; k0 < HIDDEN; k0 += 32) {
        float4 av[4];
#pragma unroll
        for (int i = 0; i < 4; ++i) av[i] = *(const float4*)(xp + k0 + i * 4);
        float bv[16];
#pragma unroll
        for (int i = 0; i < 16; ++i) bv[i] = wp[(size_t)(k0 + i) * HALF];

        __syncthreads();
        {
            unsigned short hi[16], lo[16];
#pragma unroll
            for (int i = 0; i < 4; ++i) {
                const float vs[4] = {av[i].x, av[i].y, av[i].z, av[i].w};
#pragma unroll
                for (int j = 0; j < 4; ++j) {
                    float v = vs[j];
                    unsigned short hb = bf16_rne(v);
                    hi[i * 4 + j] = hb;
                    lo[i * 4 + j] = bf16_rne(v - bf16_to_f(hb));
                }
            }
            *(short8*)&Ah[sm][kh]     = *(const short8*)&hi[0];
            *(short8*)&Ah[sm][kh + 8] = *(const short8*)&hi[8];
            *(short8*)&Al[sm][kh]     = *(const short8*)&lo[0];
            *(short8*)&Al[sm][kh + 8] = *(const short8*)&lo[8];
        }
        {
            unsigned short hi[16], lo[16];
#pragma unroll
            for (int i = 0; i < 16; ++i) {
                float v = bv[i];
                unsigned short hb = bf16_rne(v);
                hi[i] = hb;
                lo[i] = bf16_rne(v - bf16_to_f(hb));
            }
            *(short8*)&Bh[sm][kh]     = *(const short8*)&hi[0];
            *(short8*)&Bh[sm][kh + 8] = *(const short8*)&hi[8];
            *(short8*)&Bl[sm][kh]     = *(const short8*)&lo[0];
            *(short8*)&Bl[sm][kh + 8] = *(const short8*)&lo[8];
        }
        __syncthreads();

        short8 a_hi[4], a_lo[4], b_hi[4], b_lo[4];
#pragma unroll
        for (int t = 0; t < 4; ++t) {
            a_hi[t] = *(const short8*)&Ah[wm + t * 16 + l15][q * 8];
            a_lo[t] = *(const short8*)&Al[wm + t * 16 + l15][q * 8];
            b_hi[t] = *(const short8*)&Bh[wn + t * 16 + l15][q * 8];
            b_lo[t] = *(const short8*)&Bl[wn + t * 16 + l15][q * 8];
        }
#pragma unroll
        for (int i = 0; i < 4; ++i)
#pragma unroll
            for (int j = 0; j < 4; ++j) {
                acc[i][j] = __builtin_amdgcn_mfma_f32_16x16x32_bf16(a_hi[i], b_hi[j], acc[i][j], 0, 0, 0);
                acc[i][j] = __builtin_amdgcn_mfma_f32_16x16x32_bf16(a_lo[i], b_hi[j], acc[i][j], 0, 0, 0);
                acc[i][j] = __builtin_amdgcn_mfma_f32_16x16x32_bf16(a_hi[i], b_lo[j], acc[i][j], 0, 0, 0);
            }
    }

#pragma unroll
    for (int j = 0; j < 4; ++j) {
        const int n = n0 + wn + j * 16 + l15;
        const float bb = bias1[n];
#pragma unroll
        for (int i = 0; i < 4; ++i) {
            const int mbase = m0 + wm + i * 16 + q * 4;
#pragma unroll
            for (int r = 0; r < 4; ++r) {
                float v = acc[i][j][r] + bb;
                float g = 0.5f * v * (1.0f + erff(v * 0.70710678118654752f));
                hstore(h + (size_t)(mbase + r) * HALF + n, g);
            }
        }
    }
}

// ---------------------------------------------------------------------------
// K2: logits[T,64] = h[T,2048] @ W2[2048,64] + b2. One block per token.
// ---------------------------------------------------------------------------
template <typename HT>
__global__ __launch_bounds__(256) void gemm2(const HT* __restrict__ h,
                                             const float* __restrict__ W2,
                                             const float* __restrict__ bias2,
                                             float* __restrict__ logits) {
    __shared__ float hs[HALF];
    __shared__ float red[4][NE];
    const int tid = threadIdx.x;
    const size_t r = blockIdx.x;
    const HT* hr = h + r * HALF;
    for (int i = tid; i < HALF; i += 256) hs[i] = hload(hr + i);
    __syncthreads();
    const int e = tid & 63, qq = tid >> 6;
    float s = 0.f;
    const float* w = W2 + e;
#pragma unroll 8
    for (int k = qq * 512; k < qq * 512 + 512; ++k)
        s = fmaf(hs[k], w[(size_t)k * NE], s);
    red[qq][e] = s;
    __syncthreads();
    if (tid < 64)
        logits[r * NE + tid] = ((red[0][tid] + red[1][tid]) + (red[2][tid] + red[3][tid])) + bias2[tid];
}

// ---------------------------------------------------------------------------
// K3: per-token top-8 + softmax + scatter + mask. One wave per token.
// ---------------------------------------------------------------------------
__global__ __launch_bounds__(256) void topk_softmax(const float* __restrict__ logits,
                                                    const float* __restrict__ amask,
                                                    float* __restrict__ out, int T) {
    const int wave = threadIdx.x >> 6;
    const int lane = threadIdx.x & 63;
    const int r = blockIdx.x * 4 + wave;
    if (r >= T) return;

    const float v  = logits[(size_t)r * NE + lane];
    const float mk = amask[r];

    out[(size_t)T * NE + (size_t)r * NE + lane] = v * mk;   // router_logits

    bool  sel = false;
    float m0 = 0.f, Z = 0.f;
#pragma unroll
    for (int it = 0; it < TOPK; ++it) {
        float cand = sel ? -INFINITY : v;
        int   idx  = lane;
#pragma unroll
        for (int off = 32; off; off >>= 1) {
            float ov = __shfl_xor(cand, off, 64);
            int   oi = __shfl_xor(idx,  off, 64);
            if (ov > cand || (ov == cand && oi < idx)) { cand = ov; idx = oi; }
        }
        if (it == 0) m0 = cand;
        Z += expf(cand - m0);
        if (lane == idx) sel = true;
    }
    const float w = sel ? (expf(v - m0) / Z) : 0.f;
    out[(size_t)r * NE + lane] = w * mk;
}

// ---------------------------------------------------------------------------
extern "C" void kernel_launch(void* const* d_in, const int* in_sizes, int n_in,
                              void* d_out, int out_size, void* d_ws, size_t ws_size,
                              hipStream_t stream) {
    const float* x   = (const float*)d_in[0];
    const float* am  = (const float*)d_in[1];
    const float* W1  = (const float*)d_in[2];
    const float* b1  = (const float*)d_in[3];
    const float* W2  = (const float*)d_in[4];
    const float* b2  = (const float*)d_in[5];
    float* out = (float*)d_out;

    const int T = in_sizes[0] / HIDDEN;   // 16384

    const size_t logits_bytes = (size_t)T * NE * sizeof(float);      // 4 MB
    const size_t h32_bytes    = (size_t)T * HALF * sizeof(float);    // 134 MB
    const size_t xsplit_bytes = (size_t)T * HIDDEN * 2;              // 134 MB each
    const size_t wsplit_bytes = (size_t)HIDDEN * HALF * 2;           // 16.8 MB each
    const size_t need_new = logits_bytes + h32_bytes + 2 * xsplit_bytes + 2 * wsplit_bytes;

    float* logits = (float*)d_ws;
    dim3 g1(T / 128, HALF / 128);

    if (ws_size >= need_new) {
        char* p = (char*)d_ws + logits_bytes;
        float* h = (float*)p;                     p += h32_bytes;
        unsigned short* xhp = (unsigned short*)p; p += xsplit_bytes;
        unsigned short* xlp = (unsigned short*)p; p += xsplit_bytes;
        unsigned short* whp = (unsigned short*)p; p += wsplit_bytes;
        unsigned short* wlp = (unsigned short*)p;

        const size_t xN = (size_t)T * HIDDEN;
        hipLaunchKernelGGL(split_x_k, dim3(xN / (4 * 256)), dim3(256), 0, stream, x, xhp, xlp);
        hipLaunchKernelGGL(split_wt_k, dim3(HIDDEN / 64, HALF / 64), dim3(256), 0, stream, W1, whp, wlp);
        hipLaunchKernelGGL(gemm1_gelu_pre, g1, dim3(256), 0, stream, xhp, xlp, whp, wlp, b1, h);
        hipLaunchKernelGGL((gemm2<float>), dim3(T), dim3(256), 0, stream, h, W2, b2, logits);
    } else if (ws_size >= logits_bytes + h32_bytes) {
        float* h = (float*)((char*)d_ws + logits_bytes);
        hipLaunchKernelGGL((gemm1_gelu_mfma<float>), g1, dim3(256), 0, stream, x, W1, b1, h);
        hipLaunchKernelGGL((gemm2<float>), dim3(T), dim3(256), 0, stream, h, W2, b2, logits);
    } else {
        __hip_bfloat16* h = (__hip_bfloat16*)((char*)d_ws + logits_bytes);
        hipLaunchKernelGGL((gemm1_gelu_mfma<__hip_bfloat16>), g1, dim3(256), 0, stream, x, W1, b1, h);
        hipLaunchKernelGGL((gemm2<__hip_bfloat16>), dim3(T), dim3(256), 0, stream, h, W2, b2, logits);
    }
    hipLaunchKernelGGL(topk_softmax, dim3(T / 4), dim3(256), 0, stream, logits, am, out, T);
}

// Round 6
// 1509.520 us; speedup vs baseline: 1.1403x; 1.1403x over previous
//
#include <hip/hip_runtime.h>
#include <hip/hip_bf16.h>
#include <math.h>

#define HIDDEN 4096
#define HALF   2048
#define NE     64
#define TOPK   8

typedef __attribute__((ext_vector_type(8))) short          short8;
typedef __attribute__((ext_vector_type(4))) float          floatx4;
typedef __attribute__((ext_vector_type(4))) unsigned short ushort4v;

// ---------- bf16 split helpers ------------------------------------------------
__device__ inline unsigned short bf16_rne(float v) {
    union { float f; unsigned u; } x; x.f = v;
    unsigned r = x.u + 0x7fffu + ((x.u >> 16) & 1u);
    return (unsigned short)(r >> 16);
}
__device__ inline float bf16_to_f(unsigned short b) {
    union { unsigned u; float f; } x; x.u = (unsigned)b << 16;
    return x.f;
}

// ---------- h storage precision helpers (fallback paths) ----------------------
__device__ inline void hstore(float* p, float v) { *p = v; }
__device__ inline void hstore(__hip_bfloat16* p, float v) { *p = __float2bfloat16(v); }
__device__ inline float hload(const float* p) { return *p; }
__device__ inline float hload(const __hip_bfloat16* p) { return __bfloat162float(*p); }

// ---------- async global->LDS, 16B per lane -----------------------------------
__device__ inline void gl2lds16(const void* g, void* l) {
    __builtin_amdgcn_global_load_lds(
        (const __attribute__((address_space(1))) void*)g,
        (__attribute__((address_space(3))) void*)l, 16, 0, 0);
}

// ---------------------------------------------------------------------------
// P1: split x[T*4096] fp32 -> xh, xl bf16 (4 elems/thread)
// ---------------------------------------------------------------------------
__global__ __launch_bounds__(256) void split_x_k(const float* __restrict__ x,
                                                 unsigned short* __restrict__ hi,
                                                 unsigned short* __restrict__ lo) {
    const size_t i = ((size_t)blockIdx.x * 256 + threadIdx.x) * 4;
    float4 v = *(const float4*)(x + i);
    const float vs[4] = {v.x, v.y, v.z, v.w};
    ushort4v h4, l4;
#pragma unroll
    for (int j = 0; j < 4; ++j) {
        unsigned short hb = bf16_rne(vs[j]);
        h4[j] = hb;
        l4[j] = bf16_rne(vs[j] - bf16_to_f(hb));
    }
    *(ushort4v*)(hi + i) = h4;
    *(ushort4v*)(lo + i) = l4;
}

// ---------------------------------------------------------------------------
// P2: src[K][N] fp32 row-major -> transposed hi/lo [N][K] bf16.
// K = src ROW count, N = src COLUMN count. Grid (K/64, N/64), 256 thr.
// W1: (HIDDEN, HALF) -> grid (HIDDEN/64, HALF/64), args K=HIDDEN, N=HALF.
// ---------------------------------------------------------------------------
__global__ __launch_bounds__(256) void split_wt_k(const float* __restrict__ src,
                                                  unsigned short* __restrict__ wh,
                                                  unsigned short* __restrict__ wl,
                                                  int K, int N) {
    __shared__ float tile[64][65];
    const int tid = threadIdx.x;
    const int bk = blockIdx.x * 64, bn = blockIdx.y * 64;
    const int c4 = (tid & 15) * 4, r = tid >> 4;   // r in 0..15
#pragma unroll
    for (int rr = 0; rr < 4; ++rr) {
        const int row = r + rr * 16;
        *(float4*)&tile[row][c4] = *(const float4*)&src[(size_t)(bk + row) * N + bn + c4];
    }
    __syncthreads();
#pragma unroll
    for (int rr = 0; rr < 4; ++rr) {
        const int n = r + rr * 16;
        ushort4v h4, l4;
#pragma unroll
        for (int j = 0; j < 4; ++j) {
            float v = tile[c4 + j][n];
            unsigned short hb = bf16_rne(v);
            h4[j] = hb;
            l4[j] = bf16_rne(v - bf16_to_f(hb));
        }
        *(ushort4v*)&wh[(size_t)(bn + n) * K + bk + c4] = h4;
        *(ushort4v*)&wl[(size_t)(bn + n) * K + bk + c4] = l4;
    }
}

// ---------------------------------------------------------------------------
// K1 (pre-split): h = gelu_exact(x @ W1 + b1), 3-pass split-bf16 MFMA.
// Identical MFMA/epilogue arithmetic to the round-3 PASSING kernel (fp32 h) —
// only the blockIdx->(m,n) mapping changed (XCD-aligned swizzle, no FP change).
// Swizzle: 1D grid 2048. p=id>>10 (phase), j=id&1023, n_t=(j&7)|(p<<3),
// m_t=j>>3. Under round-robin XCD dispatch (id%8=XCD), each XCD works ONE
// 4MB B-tile per phase (L2-resident) and all XCDs sweep m together (A-tile
// fetched ~once from HBM, shared via LLC).
// ---------------------------------------------------------------------------
__global__ __launch_bounds__(256, 2) void gemm1_gelu_pre(const unsigned short* __restrict__ xh,
                                                         const unsigned short* __restrict__ xl,
                                                         const unsigned short* __restrict__ wh,
                                                         const unsigned short* __restrict__ wl,
                                                         const float* __restrict__ bias1,
                                                         float* __restrict__ h) {
    __shared__ unsigned short Ah[128][32];
    __shared__ unsigned short Al[128][32];
    __shared__ unsigned short Bh[128][32];
    __shared__ unsigned short Bl[128][32];

    const int tid  = threadIdx.x;
    const int id   = blockIdx.x;
    const int p    = id >> 10;
    const int j    = id & 1023;
    const int m0   = (j >> 3) * 128;
    const int n0   = (((j & 7) << 1 | p) ^ p) * 128;   // (j&7)|(p<<3) reordered-safe
    // NOTE: decode must be bijective over id in [0,2048): n_t=(j&7)+8*p, m_t=j>>3.
    const int n0_  = ((j & 7) + 8 * p) * 128;
    const int N0   = n0_;  (void)n0;

    const int wave = tid >> 6, lane = tid & 63;
    const int wm   = (wave & 1) * 64;
    const int wn   = (wave >> 1) * 64;
    const int l15  = lane & 15;
    const int q    = lane >> 4;

    const size_t lrow = (size_t)(lane >> 2);
    const int    lcol = (lane & 3) * 8;
    const unsigned short* gp;
    unsigned short* lp;
    if (wave == 0)      { gp = xh + (m0 + lrow) * HIDDEN + lcol; lp = &Ah[0][0]; }
    else if (wave == 1) { gp = xl + (m0 + lrow) * HIDDEN + lcol; lp = &Al[0][0]; }
    else if (wave == 2) { gp = wh + (N0 + lrow) * HIDDEN + lcol; lp = &Bh[0][0]; }
    else                { gp = wl + (N0 + lrow) * HIDDEN + lcol; lp = &Bl[0][0]; }

    floatx4 acc[4][4];
#pragma unroll
    for (int i = 0; i < 4; ++i)
#pragma unroll
        for (int jj = 0; jj < 4; ++jj) acc[i][jj] = (floatx4)0.f;

    for (int k0 = 0; k0 < HIDDEN; k0 += 32) {
        __syncthreads();
#pragma unroll
        for (int s = 0; s < 8; ++s)
            gl2lds16(gp + (size_t)s * 16 * HIDDEN, lp + s * 512);
        gp += 32;
        __syncthreads();

        short8 a_hi[4], a_lo[4], b_hi[4], b_lo[4];
#pragma unroll
        for (int t = 0; t < 4; ++t) {
            a_hi[t] = *(const short8*)&Ah[wm + t * 16 + l15][q * 8];
            a_lo[t] = *(const short8*)&Al[wm + t * 16 + l15][q * 8];
            b_hi[t] = *(const short8*)&Bh[wn + t * 16 + l15][q * 8];
            b_lo[t] = *(const short8*)&Bl[wn + t * 16 + l15][q * 8];
        }
#pragma unroll
        for (int i = 0; i < 4; ++i)
#pragma unroll
            for (int jj = 0; jj < 4; ++jj) {
                acc[i][jj] = __builtin_amdgcn_mfma_f32_16x16x32_bf16(a_hi[i], b_hi[jj], acc[i][jj], 0, 0, 0);
                acc[i][jj] = __builtin_amdgcn_mfma_f32_16x16x32_bf16(a_lo[i], b_hi[jj], acc[i][jj], 0, 0, 0);
                acc[i][jj] = __builtin_amdgcn_mfma_f32_16x16x32_bf16(a_hi[i], b_lo[jj], acc[i][jj], 0, 0, 0);
            }
    }

    // epilogue: +bias, exact GELU, fp32 h (bit-identical to round-3).
#pragma unroll
    for (int jj = 0; jj < 4; ++jj) {
        const int n = N0 + wn + jj * 16 + l15;
        const float bb = bias1[n];
#pragma unroll
        for (int i = 0; i < 4; ++i) {
            const int mbase = m0 + wm + i * 16 + q * 4;
#pragma unroll
            for (int r = 0; r < 4; ++r) {
                float v = acc[i][jj][r] + bb;
                float g = 0.5f * v * (1.0f + erff(v * 0.70710678118654752f));
                h[(size_t)(mbase + r) * HALF + n] = g;
            }
        }
    }
}

// ---------------------------------------------------------------------------
// K2: logits = h @ W2 + b2, 4 tokens per block.
// Per-token arithmetic is BIT-IDENTICAL to the round-3 scalar gemm2:
// thread (e=tid&63, q=tid>>6) runs s_t = sequential fmaf chain over
// k = q*512 .. q*512+511 in ascending k, then ((r0+r1)+(r2+r3))+b2.
// The only change: one W2 load feeds 4 accumulators (4x less L2 traffic).
// ---------------------------------------------------------------------------
template <typename HT>
__global__ __launch_bounds__(256) void gemm2_4tok(const HT* __restrict__ h,
                                                  const float* __restrict__ W2,
                                                  const float* __restrict__ bias2,
                                                  float* __restrict__ logits) {
    __shared__ float hs[4][HALF];          // 32 KB
    __shared__ float red[4][4][NE];        // [q][t][e], 4 KB
    const int tid = threadIdx.x;
    const size_t r0 = (size_t)blockIdx.x * 4;

    // stage 4 h rows (flat 8192 floats)
    float* hsf = &hs[0][0];
    const HT* hr = h + r0 * HALF;
#pragma unroll
    for (int it = 0; it < 8; ++it) {
        const int i = tid * 4 + it * 1024;
        hsf[i + 0] = hload(hr + i + 0);
        hsf[i + 1] = hload(hr + i + 1);
        hsf[i + 2] = hload(hr + i + 2);
        hsf[i + 3] = hload(hr + i + 3);
    }
    __syncthreads();

    const int e = tid & 63, qq = tid >> 6;
    float s0 = 0.f, s1 = 0.f, s2 = 0.f, s3 = 0.f;
    const float* w = W2 + e;
    const int kbeg = qq * 512;
    for (int k4 = kbeg; k4 < kbeg + 512; k4 += 4) {
        float4 h0 = *(const float4*)&hs[0][k4];
        float4 h1 = *(const float4*)&hs[1][k4];
        float4 h2 = *(const float4*)&hs[2][k4];
        float4 h3 = *(const float4*)&hs[3][k4];
        float wv;
        wv = w[(size_t)(k4 + 0) * NE];
        s0 = fmaf(h0.x, wv, s0); s1 = fmaf(h1.x, wv, s1); s2 = fmaf(h2.x, wv, s2); s3 = fmaf(h3.x, wv, s3);
        wv = w[(size_t)(k4 + 1) * NE];
        s0 = fmaf(h0.y, wv, s0); s1 = fmaf(h1.y, wv, s1); s2 = fmaf(h2.y, wv, s2); s3 = fmaf(h3.y, wv, s3);
        wv = w[(size_t)(k4 + 2) * NE];
        s0 = fmaf(h0.z, wv, s0); s1 = fmaf(h1.z, wv, s1); s2 = fmaf(h2.z, wv, s2); s3 = fmaf(h3.z, wv, s3);
        wv = w[(size_t)(k4 + 3) * NE];
        s0 = fmaf(h0.w, wv, s0); s1 = fmaf(h1.w, wv, s1); s2 = fmaf(h2.w, wv, s2); s3 = fmaf(h3.w, wv, s3);
    }
    red[qq][0][e] = s0;
    red[qq][1][e] = s1;
    red[qq][2][e] = s2;
    red[qq][3][e] = s3;
    __syncthreads();
    if (tid < 64) {
        const float bb = bias2[tid];
#pragma unroll
        for (int t = 0; t < 4; ++t)
            logits[(r0 + t) * NE + tid] =
                ((red[0][t][tid] + red[1][t][tid]) + (red[2][t][tid] + red[3][t][tid])) + bb;
    }
}

// ---------------------------------------------------------------------------
// Fallback K1 (round-2): in-kernel conversion, fp32/bf16 h.
// ---------------------------------------------------------------------------
template <typename HT>
__global__ __launch_bounds__(256, 2) void gemm1_gelu_mfma(const float* __restrict__ x,
                                                          const float* __restrict__ W1,
                                                          const float* __restrict__ bias1,
                                                          HT* __restrict__ h) {
    __shared__ unsigned short Ah[128][40];
    __shared__ unsigned short Al[128][40];
    __shared__ unsigned short Bh[128][40];
    __shared__ unsigned short Bl[128][40];

    const int tid  = threadIdx.x;
    const int m0   = blockIdx.x * 128;
    const int n0   = blockIdx.y * 128;
    const int wave = tid >> 6, lane = tid & 63;
    const int wm   = (wave & 1) * 64;
    const int wn   = (wave >> 1) * 64;
    const int l15  = lane & 15;
    const int q    = lane >> 4;
    const int sm = tid & 127;
    const int kh = (tid >> 7) * 16;

    floatx4 acc[4][4];
#pragma unroll
    for (int i = 0; i < 4; ++i)
#pragma unroll
        for (int j = 0; j < 4; ++j) acc[i][j] = (floatx4)0.f;

    const float* xp = x  + (size_t)(m0 + sm) * HIDDEN + kh;
    const float* wp = W1 + (size_t)kh * HALF + n0 + sm;

    for (int k0 = 0; k0 < HIDDEN; k0 += 32) {
        float4 av[4];
#pragma unroll
        for (int i = 0; i < 4; ++i) av[i] = *(const float4*)(xp + k0 + i * 4);
        float bv[16];
#pragma unroll
        for (int i = 0; i < 16; ++i) bv[i] = wp[(size_t)(k0 + i) * HALF];

        __syncthreads();
        {
            unsigned short hi[16], lo[16];
#pragma unroll
            for (int i = 0; i < 4; ++i) {
                const float vs[4] = {av[i].x, av[i].y, av[i].z, av[i].w};
#pragma unroll
                for (int j = 0; j < 4; ++j) {
                    float v = vs[j];
                    unsigned short hb = bf16_rne(v);
                    hi[i * 4 + j] = hb;
                    lo[i * 4 + j] = bf16_rne(v - bf16_to_f(hb));
                }
            }
            *(short8*)&Ah[sm][kh]     = *(const short8*)&hi[0];
            *(short8*)&Ah[sm][kh + 8] = *(const short8*)&hi[8];
            *(short8*)&Al[sm][kh]     = *(const short8*)&lo[0];
            *(short8*)&Al[sm][kh + 8] = *(const short8*)&lo[8];
        }
        {
            unsigned short hi[16], lo[16];
#pragma unroll
            for (int i = 0; i < 16; ++i) {
                float v = bv[i];
                unsigned short hb = bf16_rne(v);
                hi[i] = hb;
                lo[i] = bf16_rne(v - bf16_to_f(hb));
            }
            *(short8*)&Bh[sm][kh]     = *(const short8*)&hi[0];
            *(short8*)&Bh[sm][kh + 8] = *(const short8*)&hi[8];
            *(short8*)&Bl[sm][kh]     = *(const short8*)&lo[0];
            *(short8*)&Bl[sm][kh + 8] = *(const short8*)&lo[8];
        }
        __syncthreads();

        short8 a_hi[4], a_lo[4], b_hi[4], b_lo[4];
#pragma unroll
        for (int t = 0; t < 4; ++t) {
            a_hi[t] = *(const short8*)&Ah[wm + t * 16 + l15][q * 8];
            a_lo[t] = *(const short8*)&Al[wm + t * 16 + l15][q * 8];
            b_hi[t] = *(const short8*)&Bh[wn + t * 16 + l15][q * 8];
            b_lo[t] = *(const short8*)&Bl[wn + t * 16 + l15][q * 8];
        }
#pragma unroll
        for (int i = 0; i < 4; ++i)
#pragma unroll
            for (int j = 0; j < 4; ++j) {
                acc[i][j] = __builtin_amdgcn_mfma_f32_16x16x32_bf16(a_hi[i], b_hi[j], acc[i][j], 0, 0, 0);
                acc[i][j] = __builtin_amdgcn_mfma_f32_16x16x32_bf16(a_lo[i], b_hi[j], acc[i][j], 0, 0, 0);
                acc[i][j] = __builtin_amdgcn_mfma_f32_16x16x32_bf16(a_hi[i], b_lo[j], acc[i][j], 0, 0, 0);
            }
    }

#pragma unroll
    for (int j = 0; j < 4; ++j) {
        const int n = n0 + wn + j * 16 + l15;
        const float bb = bias1[n];
#pragma unroll
        for (int i = 0; i < 4; ++i) {
            const int mbase = m0 + wm + i * 16 + q * 4;
#pragma unroll
            for (int r = 0; r < 4; ++r) {
                float v = acc[i][j][r] + bb;
                float g = 0.5f * v * (1.0f + erff(v * 0.70710678118654752f));
                hstore(h + (size_t)(mbase + r) * HALF + n, g);
            }
        }
    }
}

// ---------------------------------------------------------------------------
// K3: per-token top-8 + softmax + scatter + mask. One wave per token.
// ---------------------------------------------------------------------------
__global__ __launch_bounds__(256) void topk_softmax(const float* __restrict__ logits,
                                                    const float* __restrict__ amask,
                                                    float* __restrict__ out, int T) {
    const int wave = threadIdx.x >> 6;
    const int lane = threadIdx.x & 63;
    const int r = blockIdx.x * 4 + wave;
    if (r >= T) return;

    const float v  = logits[(size_t)r * NE + lane];
    const float mk = amask[r];

    out[(size_t)T * NE + (size_t)r * NE + lane] = v * mk;   // router_logits

    bool  sel = false;
    float m0 = 0.f, Z = 0.f;
#pragma unroll
    for (int it = 0; it < TOPK; ++it) {
        float cand = sel ? -INFINITY : v;
        int   idx  = lane;
#pragma unroll
        for (int off = 32; off; off >>= 1) {
            float ov = __shfl_xor(cand, off, 64);
            int   oi = __shfl_xor(idx,  off, 64);
            if (ov > cand || (ov == cand && oi < idx)) { cand = ov; idx = oi; }
        }
        if (it == 0) m0 = cand;
        Z += expf(cand - m0);
        if (lane == idx) sel = true;
    }
    const float w = sel ? (expf(v - m0) / Z) : 0.f;
    out[(size_t)r * NE + lane] = w * mk;
}

// ---------------------------------------------------------------------------
extern "C" void kernel_launch(void* const* d_in, const int* in_sizes, int n_in,
                              void* d_out, int out_size, void* d_ws, size_t ws_size,
                              hipStream_t stream) {
    const float* x   = (const float*)d_in[0];
    const float* am  = (const float*)d_in[1];
    const float* W1  = (const float*)d_in[2];
    const float* b1  = (const float*)d_in[3];
    const float* W2  = (const float*)d_in[4];
    const float* b2  = (const float*)d_in[5];
    float* out = (float*)d_out;

    const int T = in_sizes[0] / HIDDEN;   // 16384

    const size_t logits_bytes  = (size_t)T * NE * sizeof(float);      // 4 MB
    const size_t h32_bytes     = (size_t)T * HALF * sizeof(float);    // 134 MB
    const size_t xsplit_bytes  = (size_t)T * HIDDEN * 2;              // 134 MB each
    const size_t w1split_bytes = (size_t)HIDDEN * HALF * 2;           // 16.8 MB each
    const size_t need_new = logits_bytes + h32_bytes + 2 * xsplit_bytes + 2 * w1split_bytes;

    float* logits = (float*)d_ws;

    if (ws_size >= need_new) {
        char* p = (char*)d_ws + logits_bytes;
        float* h = (float*)p;                     p += h32_bytes;
        unsigned short* xhp = (unsigned short*)p; p += xsplit_bytes;
        unsigned short* xlp = (unsigned short*)p; p += xsplit_bytes;
        unsigned short* w1h = (unsigned short*)p; p += w1split_bytes;
        unsigned short* w1l = (unsigned short*)p;

        const size_t xN = (size_t)T * HIDDEN;
        hipLaunchKernelGGL(split_x_k, dim3(xN / (4 * 256)), dim3(256), 0, stream, x, xhp, xlp);
        hipLaunchKernelGGL(split_wt_k, dim3(HIDDEN / 64, HALF / 64), dim3(256), 0, stream,
                           W1, w1h, w1l, HIDDEN, HALF);
        hipLaunchKernelGGL(gemm1_gelu_pre, dim3((T / 128) * (HALF / 128)), dim3(256), 0, stream,
                           xhp, xlp, w1h, w1l, b1, h);
        hipLaunchKernelGGL((gemm2_4tok<float>), dim3(T / 4), dim3(256), 0, stream, h, W2, b2, logits);
    } else if (ws_size >= logits_bytes + h32_bytes) {
        float* h = (float*)((char*)d_ws + logits_bytes);
        hipLaunchKernelGGL((gemm1_gelu_mfma<float>), dim3(T / 128, HALF / 128), dim3(256), 0, stream,
                           x, W1, b1, h);
        hipLaunchKernelGGL((gemm2_4tok<float>), dim3(T / 4), dim3(256), 0, stream, h, W2, b2, logits);
    } else {
        __hip_bfloat16* h = (__hip_bfloat16*)((char*)d_ws + logits_bytes);
        hipLaunchKernelGGL((gemm1_gelu_mfma<__hip_bfloat16>), dim3(T / 128, HALF / 128), dim3(256), 0, stream,
                           x, W1, b1, h);
        hipLaunchKernelGGL((gemm2_4tok<__hip_bfloat16>), dim3(T / 4), dim3(256), 0, stream, h, W2, b2, logits);
    }
    hipLaunchKernelGGL(topk_softmax, dim3(T / 4), dim3(256), 0, stream, logits, am, out, T);
}

// Round 7
// 1363.660 us; speedup vs baseline: 1.2622x; 1.1070x over previous
//
#include <hip/hip_runtime.h>
#include <hip/hip_bf16.h>
#include <math.h>

#define HIDDEN 4096
#define HALF   2048
#define NE     64
#define TOPK   8

typedef __attribute__((ext_vector_type(8))) short          short8;
typedef __attribute__((ext_vector_type(4))) float          floatx4;
typedef __attribute__((ext_vector_type(4))) unsigned short ushort4v;

// ---------- bf16 split helpers ------------------------------------------------
__device__ inline unsigned short bf16_rne(float v) {
    union { float f; unsigned u; } x; x.f = v;
    unsigned r = x.u + 0x7fffu + ((x.u >> 16) & 1u);
    return (unsigned short)(r >> 16);
}
__device__ inline float bf16_to_f(unsigned short b) {
    union { unsigned u; float f; } x; x.u = (unsigned)b << 16;
    return x.f;
}

// ---------- h storage precision helpers (fallback paths) ----------------------
__device__ inline void hstore(float* p, float v) { *p = v; }
__device__ inline void hstore(__hip_bfloat16* p, float v) { *p = __float2bfloat16(v); }
__device__ inline float hload(const float* p) { return *p; }
__device__ inline float hload(const __hip_bfloat16* p) { return __bfloat162float(*p); }

// ---------- async global->LDS, 16B per lane -----------------------------------
__device__ inline void gl2lds16(const void* g, void* l) {
    __builtin_amdgcn_global_load_lds(
        (const __attribute__((address_space(1))) void*)g,
        (__attribute__((address_space(3))) void*)l, 16, 0, 0);
}

// ---------------------------------------------------------------------------
// P1: split x[T*4096] fp32 -> xh, xl bf16 (4 elems/thread)
// ---------------------------------------------------------------------------
__global__ __launch_bounds__(256) void split_x_k(const float* __restrict__ x,
                                                 unsigned short* __restrict__ hi,
                                                 unsigned short* __restrict__ lo) {
    const size_t i = ((size_t)blockIdx.x * 256 + threadIdx.x) * 4;
    float4 v = *(const float4*)(x + i);
    const float vs[4] = {v.x, v.y, v.z, v.w};
    ushort4v h4, l4;
#pragma unroll
    for (int j = 0; j < 4; ++j) {
        unsigned short hb = bf16_rne(vs[j]);
        h4[j] = hb;
        l4[j] = bf16_rne(vs[j] - bf16_to_f(hb));
    }
    *(ushort4v*)(hi + i) = h4;
    *(ushort4v*)(lo + i) = l4;
}

// ---------------------------------------------------------------------------
// P2: src[K][N] fp32 row-major -> transposed hi/lo [N][K] bf16.
// K = src ROW count, N = src COLUMN count. Grid (K/64, N/64), 256 thr.
// W1: (HIDDEN, HALF) -> grid (HIDDEN/64, HALF/64), args K=HIDDEN, N=HALF.
// ---------------------------------------------------------------------------
__global__ __launch_bounds__(256) void split_wt_k(const float* __restrict__ src,
                                                  unsigned short* __restrict__ wh,
                                                  unsigned short* __restrict__ wl,
                                                  int K, int N) {
    __shared__ float tile[64][65];
    const int tid = threadIdx.x;
    const int bk = blockIdx.x * 64, bn = blockIdx.y * 64;
    const int c4 = (tid & 15) * 4, r = tid >> 4;   // r in 0..15
#pragma unroll
    for (int rr = 0; rr < 4; ++rr) {
        const int row = r + rr * 16;
        *(float4*)&tile[row][c4] = *(const float4*)&src[(size_t)(bk + row) * N + bn + c4];
    }
    __syncthreads();
#pragma unroll
    for (int rr = 0; rr < 4; ++rr) {
        const int n = r + rr * 16;
        ushort4v h4, l4;
#pragma unroll
        for (int j = 0; j < 4; ++j) {
            float v = tile[c4 + j][n];
            unsigned short hb = bf16_rne(v);
            h4[j] = hb;
            l4[j] = bf16_rne(v - bf16_to_f(hb));
        }
        *(ushort4v*)&wh[(size_t)(bn + n) * K + bk + c4] = h4;
        *(ushort4v*)&wl[(size_t)(bn + n) * K + bk + c4] = l4;
    }
}

// ---------------------------------------------------------------------------
// K1 (pre-split): h = gelu_exact(x @ W1 + b1), 3-pass split-bf16 MFMA.
// MFMA/epilogue arithmetic BIT-IDENTICAL to the round-3/6 passing kernels —
// only the blockIdx->(m,n) decode changed (m-supertile + XCD n-affinity).
// Decode: 1D grid 2048; c=id>>9 (m-chunk of 32 m-tiles), j=id&511,
// mt=c*32+(j>>4), nt=j&15. Per chunk: x window = 67 MB (LLC-resident),
// XCD k (=id%8 under round-robin) keeps nt in {k,k+8} (4 MB B, L2-resident).
// ---------------------------------------------------------------------------
__global__ __launch_bounds__(256, 2) void gemm1_gelu_pre(const unsigned short* __restrict__ xh,
                                                         const unsigned short* __restrict__ xl,
                                                         const unsigned short* __restrict__ wh,
                                                         const unsigned short* __restrict__ wl,
                                                         const float* __restrict__ bias1,
                                                         float* __restrict__ h) {
    __shared__ unsigned short Ah[128][32];
    __shared__ unsigned short Al[128][32];
    __shared__ unsigned short Bh[128][32];
    __shared__ unsigned short Bl[128][32];

    const int tid = threadIdx.x;
    const int id  = blockIdx.x;
    const int c   = id >> 9;            // m-chunk 0..3
    const int j   = id & 511;
    const int m0  = ((c << 5) | (j >> 4)) * 128;   // mt in [c*32, c*32+32)
    const int N0  = (j & 15) * 128;                // nt 0..15, XCD = nt&7

    const int wave = tid >> 6, lane = tid & 63;
    const int wm   = (wave & 1) * 64;
    const int wn   = (wave >> 1) * 64;
    const int l15  = lane & 15;
    const int q    = lane >> 4;

    const size_t lrow = (size_t)(lane >> 2);
    const int    lcol = (lane & 3) * 8;
    const unsigned short* gp;
    unsigned short* lp;
    if (wave == 0)      { gp = xh + (m0 + lrow) * HIDDEN + lcol; lp = &Ah[0][0]; }
    else if (wave == 1) { gp = xl + (m0 + lrow) * HIDDEN + lcol; lp = &Al[0][0]; }
    else if (wave == 2) { gp = wh + (N0 + lrow) * HIDDEN + lcol; lp = &Bh[0][0]; }
    else                { gp = wl + (N0 + lrow) * HIDDEN + lcol; lp = &Bl[0][0]; }

    floatx4 acc[4][4];
#pragma unroll
    for (int i = 0; i < 4; ++i)
#pragma unroll
        for (int jj = 0; jj < 4; ++jj) acc[i][jj] = (floatx4)0.f;

    for (int k0 = 0; k0 < HIDDEN; k0 += 32) {
        __syncthreads();
#pragma unroll
        for (int s = 0; s < 8; ++s)
            gl2lds16(gp + (size_t)s * 16 * HIDDEN, lp + s * 512);
        gp += 32;
        __syncthreads();

        short8 a_hi[4], a_lo[4], b_hi[4], b_lo[4];
#pragma unroll
        for (int t = 0; t < 4; ++t) {
            a_hi[t] = *(const short8*)&Ah[wm + t * 16 + l15][q * 8];
            a_lo[t] = *(const short8*)&Al[wm + t * 16 + l15][q * 8];
            b_hi[t] = *(const short8*)&Bh[wn + t * 16 + l15][q * 8];
            b_lo[t] = *(const short8*)&Bl[wn + t * 16 + l15][q * 8];
        }
#pragma unroll
        for (int i = 0; i < 4; ++i)
#pragma unroll
            for (int jj = 0; jj < 4; ++jj) {
                acc[i][jj] = __builtin_amdgcn_mfma_f32_16x16x32_bf16(a_hi[i], b_hi[jj], acc[i][jj], 0, 0, 0);
                acc[i][jj] = __builtin_amdgcn_mfma_f32_16x16x32_bf16(a_lo[i], b_hi[jj], acc[i][jj], 0, 0, 0);
                acc[i][jj] = __builtin_amdgcn_mfma_f32_16x16x32_bf16(a_hi[i], b_lo[jj], acc[i][jj], 0, 0, 0);
            }
    }

    // epilogue: +bias, exact GELU, fp32 h (bit-identical to round-3/6).
#pragma unroll
    for (int jj = 0; jj < 4; ++jj) {
        const int n = N0 + wn + jj * 16 + l15;
        const float bb = bias1[n];
#pragma unroll
        for (int i = 0; i < 4; ++i) {
            const int mbase = m0 + wm + i * 16 + q * 4;
#pragma unroll
            for (int r = 0; r < 4; ++r) {
                float v = acc[i][jj][r] + bb;
                float g = 0.5f * v * (1.0f + erff(v * 0.70710678118654752f));
                h[(size_t)(mbase + r) * HALF + n] = g;
            }
        }
    }
}

// ---------------------------------------------------------------------------
// K2+K3 fused: logits = h @ W2 + b2 (4 tokens/block, bit-identical per-token
// fmaf chain: thread (e,q) sums k = q*512..q*512+511 ascending, then
// ((r0+r1)+(r2+r3))+b2) followed by in-block top-8 softmax + masked scatter.
// Wave w handles token r0+w; lane = expert. No logits round-trip.
// ---------------------------------------------------------------------------
template <typename HT>
__global__ __launch_bounds__(256) void gemm2_topk(const HT* __restrict__ h,
                                                  const float* __restrict__ W2,
                                                  const float* __restrict__ bias2,
                                                  const float* __restrict__ amask,
                                                  float* __restrict__ out, int T) {
    __shared__ float hs[4][HALF];          // 32 KB
    __shared__ float red[4][4][NE];        // [q][t][e], 4 KB
    const int tid = threadIdx.x;
    const size_t r0 = (size_t)blockIdx.x * 4;

    // stage 4 h rows (flat 8192 floats, coalesced)
    float* hsf = &hs[0][0];
    const HT* hr = h + r0 * HALF;
#pragma unroll
    for (int it = 0; it < 8; ++it) {
        const int i = tid * 4 + it * 1024;
        hsf[i + 0] = hload(hr + i + 0);
        hsf[i + 1] = hload(hr + i + 1);
        hsf[i + 2] = hload(hr + i + 2);
        hsf[i + 3] = hload(hr + i + 3);
    }
    __syncthreads();

    const int e = tid & 63, qq = tid >> 6;
    float s0 = 0.f, s1 = 0.f, s2 = 0.f, s3 = 0.f;
    const float* w = W2 + e;
    const int kbeg = qq * 512;
    for (int k4 = kbeg; k4 < kbeg + 512; k4 += 4) {
        float4 h0 = *(const float4*)&hs[0][k4];
        float4 h1 = *(const float4*)&hs[1][k4];
        float4 h2 = *(const float4*)&hs[2][k4];
        float4 h3 = *(const float4*)&hs[3][k4];
        float wv;
        wv = w[(size_t)(k4 + 0) * NE];
        s0 = fmaf(h0.x, wv, s0); s1 = fmaf(h1.x, wv, s1); s2 = fmaf(h2.x, wv, s2); s3 = fmaf(h3.x, wv, s3);
        wv = w[(size_t)(k4 + 1) * NE];
        s0 = fmaf(h0.y, wv, s0); s1 = fmaf(h1.y, wv, s1); s2 = fmaf(h2.y, wv, s2); s3 = fmaf(h3.y, wv, s3);
        wv = w[(size_t)(k4 + 2) * NE];
        s0 = fmaf(h0.z, wv, s0); s1 = fmaf(h1.z, wv, s1); s2 = fmaf(h2.z, wv, s2); s3 = fmaf(h3.z, wv, s3);
        wv = w[(size_t)(k4 + 3) * NE];
        s0 = fmaf(h0.w, wv, s0); s1 = fmaf(h1.w, wv, s1); s2 = fmaf(h2.w, wv, s2); s3 = fmaf(h3.w, wv, s3);
    }
    red[qq][0][e] = s0;
    red[qq][1][e] = s1;
    red[qq][2][e] = s2;
    red[qq][3][e] = s3;
    __syncthreads();

    // ---- per-wave token: final reduce (same add tree), top-8 softmax, mask
    const int wave = tid >> 6, lane = tid & 63;
    const size_t r = r0 + wave;
    const float v = ((red[0][wave][lane] + red[1][wave][lane]) +
                     (red[2][wave][lane] + red[3][wave][lane])) + bias2[lane];
    const float mk = amask[r];

    out[(size_t)T * NE + r * NE + lane] = v * mk;   // router_logits

    bool  sel = false;
    float m0 = 0.f, Z = 0.f;
#pragma unroll
    for (int it = 0; it < TOPK; ++it) {
        float cand = sel ? -INFINITY : v;
        int   idx  = lane;
#pragma unroll
        for (int off = 32; off; off >>= 1) {
            float ov = __shfl_xor(cand, off, 64);
            int   oi = __shfl_xor(idx,  off, 64);
            if (ov > cand || (ov == cand && oi < idx)) { cand = ov; idx = oi; }
        }
        if (it == 0) m0 = cand;
        Z += expf(cand - m0);
        if (lane == idx) sel = true;
    }
    const float wgt = sel ? (expf(v - m0) / Z) : 0.f;
    out[r * NE + lane] = wgt * mk;
}

// ---------------------------------------------------------------------------
// Fallback K1 (round-2): in-kernel conversion, fp32/bf16 h.
// ---------------------------------------------------------------------------
template <typename HT>
__global__ __launch_bounds__(256, 2) void gemm1_gelu_mfma(const float* __restrict__ x,
                                                          const float* __restrict__ W1,
                                                          const float* __restrict__ bias1,
                                                          HT* __restrict__ h) {
    __shared__ unsigned short Ah[128][40];
    __shared__ unsigned short Al[128][40];
    __shared__ unsigned short Bh[128][40];
    __shared__ unsigned short Bl[128][40];

    const int tid  = threadIdx.x;
    const int m0   = blockIdx.x * 128;
    const int n0   = blockIdx.y * 128;
    const int wave = tid >> 6, lane = tid & 63;
    const int wm   = (wave & 1) * 64;
    const int wn   = (wave >> 1) * 64;
    const int l15  = lane & 15;
    const int q    = lane >> 4;
    const int sm = tid & 127;
    const int kh = (tid >> 7) * 16;

    floatx4 acc[4][4];
#pragma unroll
    for (int i = 0; i < 4; ++i)
#pragma unroll
        for (int j = 0; j < 4; ++j) acc[i][j] = (floatx4)0.f;

    const float* xp = x  + (size_t)(m0 + sm) * HIDDEN + kh;
    const float* wp = W1 + (size_t)kh * HALF + n0 + sm;

    for (int k0 = 0; k0 < HIDDEN; k0 += 32) {
        float4 av[4];
#pragma unroll
        for (int i = 0; i < 4; ++i) av[i] = *(const float4*)(xp + k0 + i * 4);
        float bv[16];
#pragma unroll
        for (int i = 0; i < 16; ++i) bv[i] = wp[(size_t)(k0 + i) * HALF];

        __syncthreads();
        {
            unsigned short hi[16], lo[16];
#pragma unroll
            for (int i = 0; i < 4; ++i) {
                const float vs[4] = {av[i].x, av[i].y, av[i].z, av[i].w};
#pragma unroll
                for (int j = 0; j < 4; ++j) {
                    float v = vs[j];
                    unsigned short hb = bf16_rne(v);
                    hi[i * 4 + j] = hb;
                    lo[i * 4 + j] = bf16_rne(v - bf16_to_f(hb));
                }
            }
            *(short8*)&Ah[sm][kh]     = *(const short8*)&hi[0];
            *(short8*)&Ah[sm][kh + 8] = *(const short8*)&hi[8];
            *(short8*)&Al[sm][kh]     = *(const short8*)&lo[0];
            *(short8*)&Al[sm][kh + 8] = *(const short8*)&lo[8];
        }
        {
            unsigned short hi[16], lo[16];
#pragma unroll
            for (int i = 0; i < 16; ++i) {
                float v = bv[i];
                unsigned short hb = bf16_rne(v);
                hi[i] = hb;
                lo[i] = bf16_rne(v - bf16_to_f(hb));
            }
            *(short8*)&Bh[sm][kh]     = *(const short8*)&hi[0];
            *(short8*)&Bh[sm][kh + 8] = *(const short8*)&hi[8];
            *(short8*)&Bl[sm][kh]     = *(const short8*)&lo[0];
            *(short8*)&Bl[sm][kh + 8] = *(const short8*)&lo[8];
        }
        __syncthreads();

        short8 a_hi[4], a_lo[4], b_hi[4], b_lo[4];
#pragma unroll
        for (int t = 0; t < 4; ++t) {
            a_hi[t] = *(const short8*)&Ah[wm + t * 16 + l15][q * 8];
            a_lo[t] = *(const short8*)&Al[wm + t * 16 + l15][q * 8];
            b_hi[t] = *(const short8*)&Bh[wn + t * 16 + l15][q * 8];
            b_lo[t] = *(const short8*)&Bl[wn + t * 16 + l15][q * 8];
        }
#pragma unroll
        for (int i = 0; i < 4; ++i)
#pragma unroll
            for (int j = 0; j < 4; ++j) {
                acc[i][j] = __builtin_amdgcn_mfma_f32_16x16x32_bf16(a_hi[i], b_hi[j], acc[i][j], 0, 0, 0);
                acc[i][j] = __builtin_amdgcn_mfma_f32_16x16x32_bf16(a_lo[i], b_hi[j], acc[i][j], 0, 0, 0);
                acc[i][j] = __builtin_amdgcn_mfma_f32_16x16x32_bf16(a_hi[i], b_lo[j], acc[i][j], 0, 0, 0);
            }
    }

#pragma unroll
    for (int j = 0; j < 4; ++j) {
        const int n = n0 + wn + j * 16 + l15;
        const float bb = bias1[n];
#pragma unroll
        for (int i = 0; i < 4; ++i) {
            const int mbase = m0 + wm + i * 16 + q * 4;
#pragma unroll
            for (int r = 0; r < 4; ++r) {
                float v = acc[i][j][r] + bb;
                float g = 0.5f * v * (1.0f + erff(v * 0.70710678118654752f));
                hstore(h + (size_t)(mbase + r) * HALF + n, g);
            }
        }
    }
}

// ---------------------------------------------------------------------------
extern "C" void kernel_launch(void* const* d_in, const int* in_sizes, int n_in,
                              void* d_out, int out_size, void* d_ws, size_t ws_size,
                              hipStream_t stream) {
    const float* x   = (const float*)d_in[0];
    const float* am  = (const float*)d_in[1];
    const float* W1  = (const float*)d_in[2];
    const float* b1  = (const float*)d_in[3];
    const float* W2  = (const float*)d_in[4];
    const float* b2  = (const float*)d_in[5];
    float* out = (float*)d_out;

    const int T = in_sizes[0] / HIDDEN;   // 16384

    const size_t h32_bytes     = (size_t)T * HALF * sizeof(float);    // 134 MB
    const size_t h16_bytes     = (size_t)T * HALF * 2;                // 67 MB
    const size_t xsplit_bytes  = (size_t)T * HIDDEN * 2;              // 134 MB each
    const size_t w1split_bytes = (size_t)HIDDEN * HALF * 2;           // 16.8 MB each
    const size_t need_new = h32_bytes + 2 * xsplit_bytes + 2 * w1split_bytes;

    if (ws_size >= need_new) {
        char* p = (char*)d_ws;
        float* h = (float*)p;                     p += h32_bytes;
        unsigned short* xhp = (unsigned short*)p; p += xsplit_bytes;
        unsigned short* xlp = (unsigned short*)p; p += xsplit_bytes;
        unsigned short* w1h = (unsigned short*)p; p += w1split_bytes;
        unsigned short* w1l = (unsigned short*)p;

        const size_t xN = (size_t)T * HIDDEN;
        hipLaunchKernelGGL(split_x_k, dim3(xN / (4 * 256)), dim3(256), 0, stream, x, xhp, xlp);
        hipLaunchKernelGGL(split_wt_k, dim3(HIDDEN / 64, HALF / 64), dim3(256), 0, stream,
                           W1, w1h, w1l, HIDDEN, HALF);
        hipLaunchKernelGGL(gemm1_gelu_pre, dim3((T / 128) * (HALF / 128)), dim3(256), 0, stream,
                           xhp, xlp, w1h, w1l, b1, h);
        hipLaunchKernelGGL((gemm2_topk<float>), dim3(T / 4), dim3(256), 0, stream,
                           h, W2, b2, am, out, T);
    } else if (ws_size >= h32_bytes) {
        float* h = (float*)d_ws;
        hipLaunchKernelGGL((gemm1_gelu_mfma<float>), dim3(T / 128, HALF / 128), dim3(256), 0, stream,
                           x, W1, b1, h);
        hipLaunchKernelGGL((gemm2_topk<float>), dim3(T / 4), dim3(256), 0, stream,
                           h, W2, b2, am, out, T);
    } else {
        __hip_bfloat16* h = (__hip_bfloat16*)d_ws;
        hipLaunchKernelGGL((gemm1_gelu_mfma<__hip_bfloat16>), dim3(T / 128, HALF / 128), dim3(256), 0, stream,
                           x, W1, b1, h);
        hipLaunchKernelGGL((gemm2_topk<__hip_bfloat16>), dim3(T / 4), dim3(256), 0, stream,
                           h, W2, b2, am, out, T);
    }
}